// Round 1
// baseline (943.323 us; speedup 1.0000x reference)
//
#include <hip/hip_runtime.h>

#define IN_DIM 512
#define HID_DIM 256

typedef __bf16 bf16x8 __attribute__((ext_vector_type(8)));
typedef unsigned short ushort8 __attribute__((ext_vector_type(8)));
typedef float floatx4 __attribute__((ext_vector_type(4)));

__device__ __forceinline__ unsigned short f2bf(float x) {
    unsigned int u = __float_as_uint(x);
    u += 0x7FFFu + ((u >> 16) & 1u);
    return (unsigned short)(u >> 16);
}

// ---------------- kernel 0: w1 fp32 -> bf16 ----------------
__global__ void conv_w1_kernel(const float* __restrict__ w1,
                               unsigned short* __restrict__ w1bf, int n) {
    int i = blockIdx.x * blockDim.x + threadIdx.x;
    if (i < n) w1bf[i] = f2bf(w1[i]);
}

// ---------------- kernel 1: LN + MLP score ----------------
// 64 rows per block, 256 threads (4 waves). Wave w computes hid [w*64, w*64+64).
// LDS x tile padded to stride 520 shorts (row shift of 4 banks -> all 32 banks used).
#define XS_STRIDE 520

__global__ __launch_bounds__(256, 2) void score_kernel(
    const float* __restrict__ feats, const float* __restrict__ ln_g,
    const float* __restrict__ ln_b, const unsigned short* __restrict__ w1bf,
    const float* __restrict__ b1, const float* __restrict__ w2,
    const float* __restrict__ b2, float* __restrict__ s_out, int N) {
    __shared__ unsigned short xs[64][XS_STRIDE];
    __shared__ float spart[4][64];

    const int tid = threadIdx.x;
    const int wid = tid >> 6;
    const int lane = tid & 63;
    const int quad = lane >> 4;
    const int l16 = lane & 15;
    const int row0 = blockIdx.x * 64;
    const int c8 = lane * 8;  // this lane's 8 columns (both fp32 and bf16 index)

    // LN params for this lane's columns (constant across rows)
    const float4 g0 = *(const float4*)(ln_g + c8);
    const float4 g1 = *(const float4*)(ln_g + c8 + 4);
    const float4 h0 = *(const float4*)(ln_b + c8);
    const float4 h1 = *(const float4*)(ln_b + c8 + 4);

    // ---- stage: LayerNorm 16 rows per wave, 2 rows in flight ----
    for (int i = 0; i < 16; i += 2) {
        const int ra = (wid << 4) + i;
        const int rb = ra + 1;
        size_t rowa = (size_t)(row0 + ra);
        size_t rowb = (size_t)(row0 + rb);
        if (rowa >= (size_t)N) rowa = (size_t)N - 1;
        if (rowb >= (size_t)N) rowb = (size_t)N - 1;
        const float4 a0 = *(const float4*)(feats + rowa * IN_DIM + c8);
        const float4 a1 = *(const float4*)(feats + rowa * IN_DIM + c8 + 4);
        const float4 d0 = *(const float4*)(feats + rowb * IN_DIM + c8);
        const float4 d1 = *(const float4*)(feats + rowb * IN_DIM + c8 + 4);

        float sa = a0.x + a0.y + a0.z + a0.w + a1.x + a1.y + a1.z + a1.w;
        float qa = a0.x * a0.x + a0.y * a0.y + a0.z * a0.z + a0.w * a0.w +
                   a1.x * a1.x + a1.y * a1.y + a1.z * a1.z + a1.w * a1.w;
        float sb = d0.x + d0.y + d0.z + d0.w + d1.x + d1.y + d1.z + d1.w;
        float qb = d0.x * d0.x + d0.y * d0.y + d0.z * d0.z + d0.w * d0.w +
                   d1.x * d1.x + d1.y * d1.y + d1.z * d1.z + d1.w * d1.w;
        for (int m = 32; m; m >>= 1) {
            sa += __shfl_xor(sa, m);
            qa += __shfl_xor(qa, m);
            sb += __shfl_xor(sb, m);
            qb += __shfl_xor(qb, m);
        }
        const float mua = sa * (1.0f / IN_DIM);
        const float rsa = rsqrtf(qa * (1.0f / IN_DIM) - mua * mua + 1e-5f);
        const float mub = sb * (1.0f / IN_DIM);
        const float rsb = rsqrtf(qb * (1.0f / IN_DIM) - mub * mub + 1e-5f);

        ushort8 va, vb;
        va[0] = f2bf((a0.x - mua) * rsa * g0.x + h0.x);
        va[1] = f2bf((a0.y - mua) * rsa * g0.y + h0.y);
        va[2] = f2bf((a0.z - mua) * rsa * g0.z + h0.z);
        va[3] = f2bf((a0.w - mua) * rsa * g0.w + h0.w);
        va[4] = f2bf((a1.x - mua) * rsa * g1.x + h1.x);
        va[5] = f2bf((a1.y - mua) * rsa * g1.y + h1.y);
        va[6] = f2bf((a1.z - mua) * rsa * g1.z + h1.z);
        va[7] = f2bf((a1.w - mua) * rsa * g1.w + h1.w);
        vb[0] = f2bf((d0.x - mub) * rsb * g0.x + h0.x);
        vb[1] = f2bf((d0.y - mub) * rsb * g0.y + h0.y);
        vb[2] = f2bf((d0.z - mub) * rsb * g0.z + h0.z);
        vb[3] = f2bf((d0.w - mub) * rsb * g0.w + h0.w);
        vb[4] = f2bf((d1.x - mub) * rsb * g1.x + h1.x);
        vb[5] = f2bf((d1.y - mub) * rsb * g1.y + h1.y);
        vb[6] = f2bf((d1.z - mub) * rsb * g1.z + h1.z);
        vb[7] = f2bf((d1.w - mub) * rsb * g1.w + h1.w);
        *(ushort8*)&xs[ra][c8] = va;
        *(ushort8*)&xs[rb][c8] = vb;
    }
    __syncthreads();

    // ---- GEMM: 64 rows x 64 hid per wave, K=512 via 16x16x32 bf16 MFMA ----
    floatx4 acc[4][4];
#pragma unroll
    for (int rt = 0; rt < 4; rt++)
#pragma unroll
        for (int ht = 0; ht < 4; ht++) acc[rt][ht] = (floatx4)(0.0f);

    const int hbase = wid * 64;
    for (int kk = 0; kk < IN_DIM; kk += 32) {
        const int kc = kk + quad * 8;
        bf16x8 af[4], bf[4];
#pragma unroll
        for (int rt = 0; rt < 4; rt++) {
            af[rt] = __builtin_bit_cast(bf16x8, *(const ushort8*)&xs[rt * 16 + l16][kc]);
        }
#pragma unroll
        for (int ht = 0; ht < 4; ht++) {
            const int hid = hbase + ht * 16 + l16;
            bf[ht] = __builtin_bit_cast(bf16x8, *(const ushort8*)(w1bf + hid * IN_DIM + kc));
        }
#pragma unroll
        for (int rt = 0; rt < 4; rt++)
#pragma unroll
            for (int ht = 0; ht < 4; ht++)
                acc[rt][ht] = __builtin_amdgcn_mfma_f32_16x16x32_bf16(af[rt], bf[ht], acc[rt][ht], 0, 0, 0);
    }
    __syncthreads();  // all waves done reading xs

    // ---- epilogue: +b1, exact GELU, dot w2, reduce across 16 cols ----
    float w2v[4], b1v[4];
#pragma unroll
    for (int ht = 0; ht < 4; ht++) {
        const int hid = hbase + ht * 16 + l16;
        w2v[ht] = w2[hid];
        b1v[ht] = b1[hid];
    }
    float p[4][4];
#pragma unroll
    for (int rt = 0; rt < 4; rt++) {
#pragma unroll
        for (int reg = 0; reg < 4; reg++) {
            float t = 0.0f;
#pragma unroll
            for (int ht = 0; ht < 4; ht++) {
                const float hv = acc[rt][ht][reg] + b1v[ht];
                t += 0.5f * hv * (1.0f + erff(hv * 0.70710678118654752f)) * w2v[ht];
            }
            p[rt][reg] = t;
        }
    }
#pragma unroll
    for (int m = 1; m < 16; m <<= 1)
#pragma unroll
        for (int rt = 0; rt < 4; rt++)
#pragma unroll
            for (int reg = 0; reg < 4; reg++) p[rt][reg] += __shfl_xor(p[rt][reg], m);
    if (l16 == 0) {
#pragma unroll
        for (int rt = 0; rt < 4; rt++)
#pragma unroll
            for (int reg = 0; reg < 4; reg++)
                spart[wid][rt * 16 + quad * 4 + reg] = p[rt][reg];
    }
    __syncthreads();
    if (tid < 64) {
        const int row = row0 + tid;
        if (row < N) {
            s_out[row] = spart[0][tid] + spart[1][tid] + spart[2][tid] + spart[3][tid] + b2[0];
        }
    }
}

// ---------------- kernel 2: per-segment max & exp-sum ----------------
__global__ void segstat_kernel(const float* __restrict__ s, const int* __restrict__ offsets,
                               float* __restrict__ smax, float* __restrict__ denom, int nseg) {
    const int seg = blockIdx.x;
    const int st = offsets[seg];
    const int en = offsets[seg + 1];
    const int tid = threadIdx.x;
    __shared__ float red[8];
    float m = -3.4e38f;
    for (int i = st + tid; i < en; i += 256) m = fmaxf(m, s[i]);
    for (int mm = 32; mm; mm >>= 1) m = fmaxf(m, __shfl_xor(m, mm));
    if ((tid & 63) == 0) red[tid >> 6] = m;
    __syncthreads();
    const float M = fmaxf(fmaxf(red[0], red[1]), fmaxf(red[2], red[3]));
    float sum = 0.0f;
    for (int i = st + tid; i < en; i += 256) sum += expf(s[i] - M);
    for (int mm = 32; mm; mm >>= 1) sum += __shfl_xor(sum, mm);
    if ((tid & 63) == 0) red[4 + (tid >> 6)] = sum;
    __syncthreads();
    if (tid == 0) {
        smax[seg] = M;
        denom[seg] = red[4] + red[5] + red[6] + red[7];
    }
}

// ---------------- kernel 3: weighted pooling ----------------
#define CHUNK 512
__global__ __launch_bounds__(256) void pool_kernel(
    const float* __restrict__ feats, const float* __restrict__ s,
    const float* __restrict__ smax, const float* __restrict__ denom,
    const int* __restrict__ offsets, int nseg, float* __restrict__ out, int N) {
    __shared__ float wbuf[CHUNK];
    __shared__ int sbuf[CHUNK];
    const int tid = threadIdx.x;
    const int r0 = blockIdx.x * CHUNK;
    const int nrows = min(CHUNK, N - r0);

    for (int r = tid; r < CHUNK; r += 256) {
        const int row = r0 + r;
        float wv = 0.0f;
        int sg = 0;
        if (row < N) {
            int lo = 0, hi = nseg;
            while (hi - lo > 1) {
                const int mid = (lo + hi) >> 1;
                if (offsets[mid] <= row) lo = mid; else hi = mid;
            }
            sg = lo;
            wv = expf(s[row] - smax[sg]) / denom[sg];
        }
        wbuf[r] = wv;
        sbuf[r] = sg;
    }
    __syncthreads();

    const int seg0 = sbuf[0];
    const int segl = sbuf[nrows - 1];
    const int d = 2 * tid;
    if (seg0 == segl) {
        float ax = 0.0f, ay = 0.0f;
        const float* fp = feats + (size_t)r0 * IN_DIM + d;
#pragma unroll 8
        for (int r = 0; r < nrows; r++) {
            const float2 f = *(const float2*)(fp + (size_t)r * IN_DIM);
            const float wv = wbuf[r];
            ax += wv * f.x;
            ay += wv * f.y;
        }
        atomicAdd(&out[seg0 * IN_DIM + d], ax);
        atomicAdd(&out[seg0 * IN_DIM + d + 1], ay);
    } else {
        // generic (segment boundary inside chunk) — correct but slow; never hit
        // with uniform offsets.
        for (int r = 0; r < nrows; r++) {
            const float2 f = *(const float2*)(feats + (size_t)(r0 + r) * IN_DIM + d);
            const float wv = wbuf[r];
            const int sg = sbuf[r];
            if (wv != 0.0f) {
                atomicAdd(&out[sg * IN_DIM + d], wv * f.x);
                atomicAdd(&out[sg * IN_DIM + d + 1], wv * f.y);
            }
        }
    }
}

extern "C" void kernel_launch(void* const* d_in, const int* in_sizes, int n_in,
                              void* d_out, int out_size, void* d_ws, size_t ws_size,
                              hipStream_t stream) {
    const float* feats = (const float*)d_in[0];
    const float* ln_g = (const float*)d_in[1];
    const float* ln_b = (const float*)d_in[2];
    const float* w1 = (const float*)d_in[3];
    const float* b1 = (const float*)d_in[4];
    const float* w2 = (const float*)d_in[5];
    const float* b2 = (const float*)d_in[6];
    const int* offsets = (const int*)d_in[7];
    const int N = in_sizes[0] / IN_DIM;
    const int nseg = in_sizes[7] - 1;
    float* out = (float*)d_out;

    // ws layout: [w1 bf16: 256 KiB][s: N*4][smax: nseg*4][denom: nseg*4]  (~1.31 MiB)
    char* ws = (char*)d_ws;
    unsigned short* w1bf = (unsigned short*)ws;
    float* s_arr = (float*)(ws + (size_t)HID_DIM * IN_DIM * 2);
    float* smax = (float*)(ws + (size_t)HID_DIM * IN_DIM * 2 + (size_t)N * 4);
    float* denom = smax + nseg;

    hipMemsetAsync(d_out, 0, (size_t)out_size * sizeof(float), stream);
    conv_w1_kernel<<<(HID_DIM * IN_DIM + 255) / 256, 256, 0, stream>>>(w1, w1bf, HID_DIM * IN_DIM);
    score_kernel<<<(N + 63) / 64, 256, 0, stream>>>(feats, ln_g, ln_b, w1bf, b1, w2, b2, s_arr, N);
    segstat_kernel<<<nseg, 256, 0, stream>>>(s_arr, offsets, smax, denom, nseg);
    pool_kernel<<<(N + CHUNK - 1) / CHUNK, 256, 0, stream>>>(feats, s_arr, smax, denom, offsets, nseg, out, N);
}

// Round 2
// 941.039 us; speedup vs baseline: 1.0024x; 1.0024x over previous
//
#include <hip/hip_runtime.h>

#define IN_DIM 512
#define HID_DIM 256
#define XS_STRIDE 520  // shorts; 1040 B/row, 16B-aligned for b128

typedef __bf16 bf16x8 __attribute__((ext_vector_type(8)));
typedef unsigned short ushort8 __attribute__((ext_vector_type(8)));
typedef float floatx4 __attribute__((ext_vector_type(4)));

__device__ __forceinline__ unsigned short f2bf_rne(float x) {
    unsigned int u = __float_as_uint(x);
    u += 0x7FFFu + ((u >> 16) & 1u);
    return (unsigned short)(u >> 16);
}

// pack two floats to bf16x2 (round-half-up: +0x8000 then take high halves via v_perm)
__device__ __forceinline__ unsigned int pack_bf2(float lo, float hi) {
    const unsigned int u0 = __float_as_uint(lo) + 0x8000u;
    const unsigned int u1 = __float_as_uint(hi) + 0x8000u;
    return __builtin_amdgcn_perm(u1, u0, 0x07060302u);
}

// ---------------- kernel 0: fold ln_g/ln_b into w1 ----------------
// w1g[h][k] = bf16(w1[h][k]*g[k]); gw[h] = sum_k w1[h][k]*g[k];
// c1[h] = sum_k w1[h][k]*b[k] + b1[h].   1 wave per hid row.
__global__ void prep_w1_kernel(const float* __restrict__ w1, const float* __restrict__ ln_g,
                               const float* __restrict__ ln_b, const float* __restrict__ b1,
                               unsigned short* __restrict__ w1g, float* __restrict__ gw,
                               float* __restrict__ c1) {
    const int wid = threadIdx.x >> 6;
    const int lane = threadIdx.x & 63;
    const int h = blockIdx.x * 4 + wid;
    const int c8 = lane * 8;
    const float4 wv0 = *(const float4*)(w1 + (size_t)h * IN_DIM + c8);
    const float4 wv1 = *(const float4*)(w1 + (size_t)h * IN_DIM + c8 + 4);
    const float4 g0 = *(const float4*)(ln_g + c8);
    const float4 g1 = *(const float4*)(ln_g + c8 + 4);
    const float4 bb0 = *(const float4*)(ln_b + c8);
    const float4 bb1 = *(const float4*)(ln_b + c8 + 4);
    float wg[8] = {wv0.x * g0.x, wv0.y * g0.y, wv0.z * g0.z, wv0.w * g0.w,
                   wv1.x * g1.x, wv1.y * g1.y, wv1.z * g1.z, wv1.w * g1.w};
    float sg = wg[0] + wg[1] + wg[2] + wg[3] + wg[4] + wg[5] + wg[6] + wg[7];
    float sb = wv0.x * bb0.x + wv0.y * bb0.y + wv0.z * bb0.z + wv0.w * bb0.w +
               wv1.x * bb1.x + wv1.y * bb1.y + wv1.z * bb1.z + wv1.w * bb1.w;
    ushort8 outv;
#pragma unroll
    for (int j = 0; j < 8; j++) outv[j] = f2bf_rne(wg[j]);
    *(ushort8*)(w1g + (size_t)h * IN_DIM + c8) = outv;
    for (int m = 32; m; m >>= 1) {
        sg += __shfl_xor(sg, m);
        sb += __shfl_xor(sb, m);
    }
    if (lane == 0) {
        gw[h] = sg;
        c1[h] = sb + b1[h];
    }
}

// ---------------- kernel 1: score (raw-bf16 GEMM + LN folded into epilogue) --
// 64 rows/block, 256 threads (4 waves). Wave w computes hid [w*64, w*64+64)
// and row-stats for rows [w*16, w*16+16) as a side-product of its A reads.
__global__ __launch_bounds__(256, 2) void score_kernel(
    const float* __restrict__ feats, const unsigned short* __restrict__ w1g,
    const float* __restrict__ gw, const float* __restrict__ c1,
    const float* __restrict__ w2, const float* __restrict__ b2,
    float* __restrict__ s_out, int N) {
    __shared__ unsigned short xs[64][XS_STRIDE];
    __shared__ float spart[4][64];
    __shared__ float2 stats_s[64];

    const int tid = threadIdx.x;
    const int wid = tid >> 6;
    const int lane = tid & 63;
    const int quad = lane >> 4;
    const int l16 = lane & 15;
    const int row0 = blockIdx.x * 64;
    const int c8 = lane * 8;

    // ---- stage raw bf16(f): pure stream, no cross-lane deps ----
#pragma unroll 4
    for (int i = 0; i < 16; i += 2) {
        const int ra = (wid << 4) + i;
        size_t rowa = (size_t)(row0 + ra);
        size_t rowb = rowa + 1;
        if (rowa >= (size_t)N) rowa = (size_t)N - 1;
        if (rowb >= (size_t)N) rowb = (size_t)N - 1;
        const float4 a0 = *(const float4*)(feats + rowa * IN_DIM + c8);
        const float4 a1 = *(const float4*)(feats + rowa * IN_DIM + c8 + 4);
        const float4 d0 = *(const float4*)(feats + rowb * IN_DIM + c8);
        const float4 d1 = *(const float4*)(feats + rowb * IN_DIM + c8 + 4);
        uint4 pa, pb;
        pa.x = pack_bf2(a0.x, a0.y);
        pa.y = pack_bf2(a0.z, a0.w);
        pa.z = pack_bf2(a1.x, a1.y);
        pa.w = pack_bf2(a1.z, a1.w);
        pb.x = pack_bf2(d0.x, d0.y);
        pb.y = pack_bf2(d0.z, d0.w);
        pb.z = pack_bf2(d1.x, d1.y);
        pb.w = pack_bf2(d1.z, d1.w);
        *(uint4*)&xs[ra][c8] = pa;
        *(uint4*)&xs[ra + 1][c8] = pb;
    }
    __syncthreads();

    // ---- GEMM 64 rows x 64 hid per wave; stats ride along on frag rt==wid --
    floatx4 acc[4][4];
#pragma unroll
    for (int rt = 0; rt < 4; rt++)
#pragma unroll
        for (int ht = 0; ht < 4; ht++) acc[rt][ht] = (floatx4)(0.0f);

    float sumf = 0.0f, sumq = 0.0f;
    const int hbase = wid * 64;
    for (int kk = 0; kk < IN_DIM; kk += 32) {
        const int kc = kk + quad * 8;
        ushort8 au[4];
        bf16x8 bf[4];
#pragma unroll
        for (int rt = 0; rt < 4; rt++) {
            au[rt] = *(const ushort8*)&xs[rt * 16 + l16][kc];
            if (rt == wid) {  // wave-uniform branch: stats for rows wid*16+l16
                const unsigned int* p = (const unsigned int*)&au[rt];
#pragma unroll
                for (int d = 0; d < 4; d++) {
                    const float lo = __uint_as_float(p[d] << 16);
                    const float hi = __uint_as_float(p[d] & 0xffff0000u);
                    sumf += lo + hi;
                    sumq += lo * lo + hi * hi;
                }
            }
        }
#pragma unroll
        for (int ht = 0; ht < 4; ht++) {
            const int hid = hbase + ht * 16 + l16;
            bf[ht] = __builtin_bit_cast(bf16x8, *(const ushort8*)(w1g + hid * IN_DIM + kc));
        }
#pragma unroll
        for (int rt = 0; rt < 4; rt++)
#pragma unroll
            for (int ht = 0; ht < 4; ht++)
                acc[rt][ht] = __builtin_amdgcn_mfma_f32_16x16x32_bf16(
                    __builtin_bit_cast(bf16x8, au[rt]), bf[ht], acc[rt][ht], 0, 0, 0);
    }

    // finalize stats: reduce across the 4 quads, write (mu, rs) for 16 rows
    sumf += __shfl_xor(sumf, 16);
    sumf += __shfl_xor(sumf, 32);
    sumq += __shfl_xor(sumq, 16);
    sumq += __shfl_xor(sumq, 32);
    if (lane < 16) {
        const float mu = sumf * (1.0f / IN_DIM);
        const float var = fmaxf(sumq * (1.0f / IN_DIM) - mu * mu, 0.0f);
        stats_s[(wid << 4) + lane] = make_float2(mu, rsqrtf(var + 1e-5f));
    }
    __syncthreads();

    // ---- epilogue: h = rs*(P - mu*gw[h]) + c1[h]; GELU; dot w2 ----
    float gwv[4], c1v[4], w2v[4];
#pragma unroll
    for (int ht = 0; ht < 4; ht++) {
        const int hid = hbase + ht * 16 + l16;
        gwv[ht] = gw[hid];
        c1v[ht] = c1[hid];
        w2v[ht] = w2[hid];
    }
    float2 st[4][4];
#pragma unroll
    for (int rt = 0; rt < 4; rt++)
#pragma unroll
        for (int reg = 0; reg < 4; reg++) st[rt][reg] = stats_s[rt * 16 + quad * 4 + reg];

    float p[4][4];
#pragma unroll
    for (int rt = 0; rt < 4; rt++) {
#pragma unroll
        for (int reg = 0; reg < 4; reg++) {
            const float mu = st[rt][reg].x, rs = st[rt][reg].y;
            float t = 0.0f;
#pragma unroll
            for (int ht = 0; ht < 4; ht++) {
                const float hv = rs * (acc[rt][ht][reg] - mu * gwv[ht]) + c1v[ht];
                t += 0.5f * hv * (1.0f + erff(hv * 0.70710678118654752f)) * w2v[ht];
            }
            p[rt][reg] = t;
        }
    }
#pragma unroll
    for (int m = 1; m < 16; m <<= 1)
#pragma unroll
        for (int rt = 0; rt < 4; rt++)
#pragma unroll
            for (int reg = 0; reg < 4; reg++) p[rt][reg] += __shfl_xor(p[rt][reg], m);
    if (l16 == 0) {
#pragma unroll
        for (int rt = 0; rt < 4; rt++)
#pragma unroll
            for (int reg = 0; reg < 4; reg++)
                spart[wid][rt * 16 + quad * 4 + reg] = p[rt][reg];
    }
    __syncthreads();
    if (tid < 64) {
        const int row = row0 + tid;
        if (row < N)
            s_out[row] = spart[0][tid] + spart[1][tid] + spart[2][tid] + spart[3][tid] + b2[0];
    }
}

// ---------------- kernel 2: per-segment max & exp-sum ----------------
__global__ void segstat_kernel(const float* __restrict__ s, const int* __restrict__ offsets,
                               float* __restrict__ smax, float* __restrict__ denom, int nseg) {
    const int seg = blockIdx.x;
    const int st = offsets[seg];
    const int en = offsets[seg + 1];
    const int tid = threadIdx.x;
    __shared__ float red[8];
    float m = -3.4e38f;
    for (int i = st + tid; i < en; i += 256) m = fmaxf(m, s[i]);
    for (int mm = 32; mm; mm >>= 1) m = fmaxf(m, __shfl_xor(m, mm));
    if ((tid & 63) == 0) red[tid >> 6] = m;
    __syncthreads();
    const float M = fmaxf(fmaxf(red[0], red[1]), fmaxf(red[2], red[3]));
    float sum = 0.0f;
    for (int i = st + tid; i < en; i += 256) sum += expf(s[i] - M);
    for (int mm = 32; mm; mm >>= 1) sum += __shfl_xor(sum, mm);
    if ((tid & 63) == 0) red[4 + (tid >> 6)] = sum;
    __syncthreads();
    if (tid == 0) {
        smax[seg] = M;
        denom[seg] = red[4] + red[5] + red[6] + red[7];
    }
}

// ---------------- kernel 3: weighted pooling ----------------
#define CHUNK 256
__global__ __launch_bounds__(256) void pool_kernel(
    const float* __restrict__ feats, const float* __restrict__ s,
    const float* __restrict__ smax, const float* __restrict__ denom,
    const int* __restrict__ offsets, int nseg, float* __restrict__ out, int N) {
    __shared__ float wbuf[CHUNK];
    __shared__ int sbuf[CHUNK];
    const int tid = threadIdx.x;
    const int r0 = blockIdx.x * CHUNK;
    const int nrows = min(CHUNK, N - r0);

    {
        const int row = r0 + tid;
        float wv = 0.0f;
        int sg = 0;
        if (row < N) {
            int lo = 0, hi = nseg;
            while (hi - lo > 1) {
                const int mid = (lo + hi) >> 1;
                if (offsets[mid] <= row) lo = mid; else hi = mid;
            }
            sg = lo;
            wv = expf(s[row] - smax[sg]) / denom[sg];
        }
        wbuf[tid] = wv;
        sbuf[tid] = sg;
    }
    __syncthreads();

    const int seg0 = sbuf[0];
    const int segl = sbuf[nrows - 1];
    const int d = 2 * tid;
    if (seg0 == segl) {
        float ax = 0.0f, ay = 0.0f;
        const float* fp = feats + (size_t)r0 * IN_DIM + d;
#pragma unroll 8
        for (int r = 0; r < nrows; r++) {
            const float2 f = *(const float2*)(fp + (size_t)r * IN_DIM);
            const float wv = wbuf[r];
            ax += wv * f.x;
            ay += wv * f.y;
        }
        atomicAdd(&out[seg0 * IN_DIM + d], ax);
        atomicAdd(&out[seg0 * IN_DIM + d + 1], ay);
    } else {
        for (int r = 0; r < nrows; r++) {
            const float2 f = *(const float2*)(feats + (size_t)(r0 + r) * IN_DIM + d);
            const float wv = wbuf[r];
            const int sg = sbuf[r];
            if (wv != 0.0f) {
                atomicAdd(&out[sg * IN_DIM + d], wv * f.x);
                atomicAdd(&out[sg * IN_DIM + d + 1], wv * f.y);
            }
        }
    }
}

extern "C" void kernel_launch(void* const* d_in, const int* in_sizes, int n_in,
                              void* d_out, int out_size, void* d_ws, size_t ws_size,
                              hipStream_t stream) {
    const float* feats = (const float*)d_in[0];
    const float* ln_g = (const float*)d_in[1];
    const float* ln_b = (const float*)d_in[2];
    const float* w1 = (const float*)d_in[3];
    const float* b1 = (const float*)d_in[4];
    const float* w2 = (const float*)d_in[5];
    const float* b2 = (const float*)d_in[6];
    const int* offsets = (const int*)d_in[7];
    const int N = in_sizes[0] / IN_DIM;
    const int nseg = in_sizes[7] - 1;
    float* out = (float*)d_out;

    // ws: [w1g bf16 256K][gw 1K][c1 1K][s N*4][smax][denom]
    char* ws = (char*)d_ws;
    unsigned short* w1g = (unsigned short*)ws;
    float* gw = (float*)(ws + (size_t)HID_DIM * IN_DIM * 2);
    float* c1 = gw + HID_DIM;
    float* s_arr = c1 + HID_DIM;
    float* smax = s_arr + N;
    float* denom = smax + nseg;

    hipMemsetAsync(d_out, 0, (size_t)out_size * sizeof(float), stream);
    prep_w1_kernel<<<HID_DIM / 4, 256, 0, stream>>>(w1, ln_g, ln_b, b1, w1g, gw, c1);
    score_kernel<<<(N + 63) / 64, 256, 0, stream>>>(feats, w1g, gw, c1, w2, b2, s_arr, N);
    segstat_kernel<<<nseg, 256, 0, stream>>>(s_arr, offsets, smax, denom, nseg);
    pool_kernel<<<(N + CHUNK - 1) / CHUNK, 256, 0, stream>>>(feats, s_arr, smax, denom, offsets, nseg, out, N);
}

// Round 3
// 901.887 us; speedup vs baseline: 1.0459x; 1.0434x over previous
//
#include <hip/hip_runtime.h>

#define IN_DIM 512
#define HID_DIM 256
#define ROWS 32          // rows per tile
#define XSS 520          // shorts per xs row (pad 8 -> bank spread, 16B aligned)

typedef __bf16 bf16x8 __attribute__((ext_vector_type(8)));
typedef unsigned short ushort8 __attribute__((ext_vector_type(8)));
typedef float floatx16 __attribute__((ext_vector_type(16)));

__device__ __forceinline__ unsigned short f2bf_rne(float x) {
    unsigned int u = __float_as_uint(x);
    u += 0x7FFFu + ((u >> 16) & 1u);
    return (unsigned short)(u >> 16);
}
__device__ __forceinline__ unsigned int pack_bf2(float lo, float hi) {
    const unsigned int u0 = __float_as_uint(lo) + 0x8000u;
    const unsigned int u1 = __float_as_uint(hi) + 0x8000u;
    return __builtin_amdgcn_perm(u1, u0, 0x07060302u);
}
// branchless exact-enough GELU (A&S 7.1.26 erf, |eps|<=1.5e-7)
__device__ __forceinline__ float gelu(float x) {
    const float ax = fabsf(x) * 0.70710678118654752f;
    const float t = __builtin_amdgcn_rcpf(1.0f + 0.3275911f * ax);
    const float y = t * (0.254829592f +
                    t * (-0.284496736f +
                    t * (1.421413741f +
                    t * (-1.453152027f + t * 1.061405429f))));
    const float e = __expf(-ax * ax);
    float er = 1.0f - y * e;
    er = __builtin_copysignf(er, x);
    return 0.5f * x * (1.0f + er);
}

// ---------------- kernel 0: fold ln_g/ln_b into w1 ----------------
__global__ void prep_w1_kernel(const float* __restrict__ w1, const float* __restrict__ ln_g,
                               const float* __restrict__ ln_b, const float* __restrict__ b1,
                               unsigned short* __restrict__ w1g, float* __restrict__ gw,
                               float* __restrict__ c1) {
    const int wid = threadIdx.x >> 6;
    const int lane = threadIdx.x & 63;
    const int h = blockIdx.x * 4 + wid;
    const int c8 = lane * 8;
    const float4 wv0 = *(const float4*)(w1 + (size_t)h * IN_DIM + c8);
    const float4 wv1 = *(const float4*)(w1 + (size_t)h * IN_DIM + c8 + 4);
    const float4 g0 = *(const float4*)(ln_g + c8);
    const float4 g1 = *(const float4*)(ln_g + c8 + 4);
    const float4 bb0 = *(const float4*)(ln_b + c8);
    const float4 bb1 = *(const float4*)(ln_b + c8 + 4);
    float wg[8] = {wv0.x * g0.x, wv0.y * g0.y, wv0.z * g0.z, wv0.w * g0.w,
                   wv1.x * g1.x, wv1.y * g1.y, wv1.z * g1.z, wv1.w * g1.w};
    float sg = wg[0] + wg[1] + wg[2] + wg[3] + wg[4] + wg[5] + wg[6] + wg[7];
    float sb = wv0.x * bb0.x + wv0.y * bb0.y + wv0.z * bb0.z + wv0.w * bb0.w +
               wv1.x * bb1.x + wv1.y * bb1.y + wv1.z * bb1.z + wv1.w * bb1.w;
    ushort8 outv;
#pragma unroll
    for (int j = 0; j < 8; j++) outv[j] = f2bf_rne(wg[j]);
    *(ushort8*)(w1g + (size_t)h * IN_DIM + c8) = outv;
    for (int m = 32; m; m >>= 1) {
        sg += __shfl_xor(sg, m);
        sb += __shfl_xor(sb, m);
    }
    if (lane == 0) {
        gw[h] = sg;
        c1[h] = sb + b1[h];
    }
}

// ---------------- kernel 1: score ----------------
// 512 threads = 8 waves. Wave w owns hid [32w,32w+32). B-slice (32 hid x 512 k)
// preloaded into 128 VGPRs once per block; k-loop touches LDS only.
// 32-row tiles, grid-stride over tiles.
__global__ __launch_bounds__(512, 2) void score_kernel(
    const float* __restrict__ feats, const unsigned short* __restrict__ w1g,
    const float* __restrict__ gw, const float* __restrict__ c1,
    const float* __restrict__ w2, const float* __restrict__ b2,
    float* __restrict__ s_out, int N, int ntiles) {
    __shared__ unsigned short xs[ROWS][XSS];
    __shared__ float2 stats_s[ROWS];
    __shared__ float spart[8][ROWS];

    const int tid = threadIdx.x;
    const int wid = tid >> 6;   // 0..7
    const int lane = tid & 63;
    const int l31 = lane & 31;
    const int hi = lane >> 5;   // 0/1
    const int hid = wid * 32 + l31;   // this lane's hid column (fixed)

    const float gwv = gw[hid];
    const float c1v = c1[hid];
    const float w2v = w2[hid];
    const float b2v = b2[0];

    // ---- B preload: w1g[hid][k], k = ki*16 + hi*8 + j ----
    bf16x8 barr[32];
    {
        const unsigned short* bp = w1g + (size_t)hid * IN_DIM + hi * 8;
#pragma unroll
        for (int ki = 0; ki < 32; ki++)
            barr[ki] = __builtin_bit_cast(bf16x8, *(const ushort8*)(bp + ki * 16));
    }

    // staging mapping: 16 lanes per row, contiguous 16B per lane per j-step
    const int srow = tid >> 4;    // 0..31
    const int schunk = tid & 15;  // 0..15

    for (int t = blockIdx.x; t < ntiles; t += gridDim.x) {
        const int row0 = t * ROWS;

        // ---- stage: fp32 load, stats, bf16 pack -> LDS ----
        {
            size_t rg = (size_t)(row0 + srow);
            if (rg >= (size_t)N) rg = (size_t)N - 1;
            const float* fp = feats + rg * IN_DIM + schunk * 4;
            float4 f[8];
#pragma unroll
            for (int j = 0; j < 8; j++) f[j] = *(const float4*)(fp + j * 64);
            float sf = 0.0f, qf = 0.0f;
#pragma unroll
            for (int j = 0; j < 8; j++) {
                sf += f[j].x + f[j].y + f[j].z + f[j].w;
                qf = fmaf(f[j].x, f[j].x, qf);
                qf = fmaf(f[j].y, f[j].y, qf);
                qf = fmaf(f[j].z, f[j].z, qf);
                qf = fmaf(f[j].w, f[j].w, qf);
            }
#pragma unroll
            for (int j = 0; j < 8; j++) {
                uint2 p;
                p.x = pack_bf2(f[j].x, f[j].y);
                p.y = pack_bf2(f[j].z, f[j].w);
                *(uint2*)&xs[srow][j * 64 + schunk * 4] = p;
            }
#pragma unroll
            for (int m = 1; m < 16; m <<= 1) {
                sf += __shfl_xor(sf, m);
                qf += __shfl_xor(qf, m);
            }
            if (schunk == 0) {
                const float mu = sf * (1.0f / IN_DIM);
                const float var = fmaxf(qf * (1.0f / IN_DIM) - mu * mu, 0.0f);
                stats_s[srow] = make_float2(mu, rsqrtf(var + 1e-5f));
            }
        }
        __syncthreads();

        // ---- k-loop: LDS A + register B, one MFMA per step ----
        floatx16 acc = (floatx16)(0.0f);
        {
            const unsigned short* ap = &xs[l31][hi * 8];
#pragma unroll
            for (int ki = 0; ki < 32; ki++) {
                const bf16x8 af = __builtin_bit_cast(bf16x8, *(const ushort8*)(ap + ki * 16));
                acc = __builtin_amdgcn_mfma_f32_32x32x16_bf16(af, barr[ki], acc, 0, 0, 0);
            }
        }

        // ---- epilogue: LN affine + GELU + w2, butterfly over 32 hid lanes ----
        float tv[16];
#pragma unroll
        for (int r = 0; r < 16; r++) {
            const int row = (r & 3) + 8 * (r >> 2) + 4 * hi;
            const float2 st = stats_s[row];
            const float hv = st.y * (acc[r] - st.x * gwv) + c1v;
            tv[r] = gelu(hv) * w2v;
        }
#pragma unroll
        for (int m = 1; m < 32; m <<= 1)
#pragma unroll
            for (int r = 0; r < 16; r++) tv[r] += __shfl_xor(tv[r], m);
        if (l31 == 0) {
#pragma unroll
            for (int r = 0; r < 16; r++)
                spart[wid][(r & 3) + 8 * (r >> 2) + 4 * hi] = tv[r];
        }
        __syncthreads();
        if (tid < ROWS) {
            const int row = row0 + tid;
            if (row < N) {
                float sv = b2v;
#pragma unroll
                for (int w = 0; w < 8; w++) sv += spart[w][tid];
                s_out[row] = sv;
            }
        }
        // next iteration's staging writes xs/stats_s (not spart) and is
        // followed by __syncthreads before spart is rewritten -> safe.
    }
}

// ---------------- kernel 2: per-segment max & exp-sum ----------------
__global__ void segstat_kernel(const float* __restrict__ s, const int* __restrict__ offsets,
                               float* __restrict__ smax, float* __restrict__ denom, int nseg) {
    const int seg = blockIdx.x;
    const int st = offsets[seg];
    const int en = offsets[seg + 1];
    const int tid = threadIdx.x;
    __shared__ float red[8];
    float m = -3.4e38f;
    for (int i = st + tid; i < en; i += 256) m = fmaxf(m, s[i]);
    for (int mm = 32; mm; mm >>= 1) m = fmaxf(m, __shfl_xor(m, mm));
    if ((tid & 63) == 0) red[tid >> 6] = m;
    __syncthreads();
    const float M = fmaxf(fmaxf(red[0], red[1]), fmaxf(red[2], red[3]));
    float sum = 0.0f;
    for (int i = st + tid; i < en; i += 256) sum += expf(s[i] - M);
    for (int mm = 32; mm; mm >>= 1) sum += __shfl_xor(sum, mm);
    if ((tid & 63) == 0) red[4 + (tid >> 6)] = sum;
    __syncthreads();
    if (tid == 0) {
        smax[seg] = M;
        denom[seg] = red[4] + red[5] + red[6] + red[7];
    }
}

// ---------------- kernel 3: weighted pooling (float4) ----------------
#define CHUNK 256
__global__ __launch_bounds__(256) void pool_kernel(
    const float* __restrict__ feats, const float* __restrict__ s,
    const float* __restrict__ smax, const float* __restrict__ denom,
    const int* __restrict__ offsets, int nseg, float* __restrict__ out, int N) {
    __shared__ float wbuf[CHUNK];
    __shared__ int sbuf[CHUNK];
    const int tid = threadIdx.x;
    const int r0 = blockIdx.x * CHUNK;
    const int nrows = min(CHUNK, N - r0);

    {
        const int row = r0 + tid;
        float wv = 0.0f;
        int sg = 0;
        if (row < N) {
            int lo = 0, hiq = nseg;
            while (hiq - lo > 1) {
                const int mid = (lo + hiq) >> 1;
                if (offsets[mid] <= row) lo = mid; else hiq = mid;
            }
            sg = lo;
            wv = expf(s[row] - smax[sg]) / denom[sg];
        }
        wbuf[tid] = wv;
        sbuf[tid] = sg;
    }
    __syncthreads();

    const int c4 = (tid & 127) * 4;
    const int half = tid >> 7;
    const int rs = half * (CHUNK / 2);
    const int re = min(rs + CHUNK / 2, nrows);
    if (re <= rs) return;

    if (sbuf[0] == sbuf[nrows - 1]) {
        const int seg = sbuf[0];
        float ax = 0.0f, ay = 0.0f, az = 0.0f, aw = 0.0f;
        const float* fp = feats + (size_t)r0 * IN_DIM + c4;
#pragma unroll 4
        for (int r = rs; r < re; r++) {
            const float4 f = *(const float4*)(fp + (size_t)r * IN_DIM);
            const float wv = wbuf[r];
            ax = fmaf(wv, f.x, ax);
            ay = fmaf(wv, f.y, ay);
            az = fmaf(wv, f.z, az);
            aw = fmaf(wv, f.w, aw);
        }
        float* op = out + (size_t)seg * IN_DIM + c4;
        atomicAdd(op + 0, ax);
        atomicAdd(op + 1, ay);
        atomicAdd(op + 2, az);
        atomicAdd(op + 3, aw);
    } else {
        for (int r = rs; r < re; r++) {
            const float4 f = *(const float4*)(feats + (size_t)(r0 + r) * IN_DIM + c4);
            const float wv = wbuf[r];
            float* op = out + (size_t)sbuf[r] * IN_DIM + c4;
            atomicAdd(op + 0, wv * f.x);
            atomicAdd(op + 1, wv * f.y);
            atomicAdd(op + 2, wv * f.z);
            atomicAdd(op + 3, wv * f.w);
        }
    }
}

extern "C" void kernel_launch(void* const* d_in, const int* in_sizes, int n_in,
                              void* d_out, int out_size, void* d_ws, size_t ws_size,
                              hipStream_t stream) {
    const float* feats = (const float*)d_in[0];
    const float* ln_g = (const float*)d_in[1];
    const float* ln_b = (const float*)d_in[2];
    const float* w1 = (const float*)d_in[3];
    const float* b1 = (const float*)d_in[4];
    const float* w2 = (const float*)d_in[5];
    const float* b2 = (const float*)d_in[6];
    const int* offsets = (const int*)d_in[7];
    const int N = in_sizes[0] / IN_DIM;
    const int nseg = in_sizes[7] - 1;
    float* out = (float*)d_out;

    char* ws = (char*)d_ws;
    unsigned short* w1g = (unsigned short*)ws;
    float* gw = (float*)(ws + (size_t)HID_DIM * IN_DIM * 2);
    float* c1 = gw + HID_DIM;
    float* s_arr = c1 + HID_DIM;
    float* smax = s_arr + N;
    float* denom = smax + nseg;

    const int ntiles = (N + ROWS - 1) / ROWS;
    int sgrid = ntiles < 2048 ? ntiles : 2048;

    hipMemsetAsync(d_out, 0, (size_t)out_size * sizeof(float), stream);
    prep_w1_kernel<<<HID_DIM / 4, 256, 0, stream>>>(w1, ln_g, ln_b, b1, w1g, gw, c1);
    score_kernel<<<sgrid, 512, 0, stream>>>(feats, w1g, gw, c1, w2, b2, s_arr, N, ntiles);
    segstat_kernel<<<nseg, 256, 0, stream>>>(s_arr, offsets, smax, denom, nseg);
    pool_kernel<<<(N + CHUNK - 1) / CHUNK, 256, 0, stream>>>(feats, s_arr, smax, denom, offsets, nseg, out, N);
}

// Round 4
// 884.307 us; speedup vs baseline: 1.0667x; 1.0199x over previous
//
#include <hip/hip_runtime.h>

#define IN_DIM 512
#define HID_DIM 256
#define ROWS 32
#define XSS 520        // shorts per xs row; pad keeps b128 alignment, spreads banks
#define PSEG 16        // partials per segment
#define PSTRIDE 516    // floats per partial record: O[512], M, d, pad

typedef __bf16 bf16x8 __attribute__((ext_vector_type(8)));
typedef unsigned short ushort8 __attribute__((ext_vector_type(8)));
typedef float floatx16 __attribute__((ext_vector_type(16)));

__device__ __forceinline__ unsigned short f2bf_rne(float x) {
    unsigned int u = __float_as_uint(x);
    u += 0x7FFFu + ((u >> 16) & 1u);
    return (unsigned short)(u >> 16);
}
__device__ __forceinline__ unsigned int pack_bf2(float lo, float hi) {
    const unsigned int u0 = __float_as_uint(lo) + 0x8000u;
    const unsigned int u1 = __float_as_uint(hi) + 0x8000u;
    return __builtin_amdgcn_perm(u1, u0, 0x07060302u);
}
// branchless erf-based GELU (A&S 7.1.26, |eps|<=1.5e-7)
__device__ __forceinline__ float gelu(float x) {
    const float ax = fabsf(x) * 0.70710678118654752f;
    const float t = __builtin_amdgcn_rcpf(1.0f + 0.3275911f * ax);
    const float y = t * (0.254829592f +
                    t * (-0.284496736f +
                    t * (1.421413741f +
                    t * (-1.453152027f + t * 1.061405429f))));
    const float e = __expf(-ax * ax);
    float er = 1.0f - y * e;
    er = __builtin_copysignf(er, x);
    return 0.5f * x * (1.0f + er);
}

// ---------------- kernel 0: fold ln_g/ln_b into w1 ----------------
__global__ void prep_w1_kernel(const float* __restrict__ w1, const float* __restrict__ ln_g,
                               const float* __restrict__ ln_b, const float* __restrict__ b1,
                               unsigned short* __restrict__ w1g, float* __restrict__ gw,
                               float* __restrict__ c1) {
    const int wid = threadIdx.x >> 6;
    const int lane = threadIdx.x & 63;
    const int h = blockIdx.x * 4 + wid;
    const int c8 = lane * 8;
    const float4 wv0 = *(const float4*)(w1 + (size_t)h * IN_DIM + c8);
    const float4 wv1 = *(const float4*)(w1 + (size_t)h * IN_DIM + c8 + 4);
    const float4 g0 = *(const float4*)(ln_g + c8);
    const float4 g1 = *(const float4*)(ln_g + c8 + 4);
    const float4 bb0 = *(const float4*)(ln_b + c8);
    const float4 bb1 = *(const float4*)(ln_b + c8 + 4);
    float wg[8] = {wv0.x * g0.x, wv0.y * g0.y, wv0.z * g0.z, wv0.w * g0.w,
                   wv1.x * g1.x, wv1.y * g1.y, wv1.z * g1.z, wv1.w * g1.w};
    float sg = wg[0] + wg[1] + wg[2] + wg[3] + wg[4] + wg[5] + wg[6] + wg[7];
    float sb = wv0.x * bb0.x + wv0.y * bb0.y + wv0.z * bb0.z + wv0.w * bb0.w +
               wv1.x * bb1.x + wv1.y * bb1.y + wv1.z * bb1.z + wv1.w * bb1.w;
    ushort8 outv;
#pragma unroll
    for (int j = 0; j < 8; j++) outv[j] = f2bf_rne(wg[j]);
    *(ushort8*)(w1g + (size_t)h * IN_DIM + c8) = outv;
    for (int m = 32; m; m >>= 1) {
        sg += __shfl_xor(sg, m);
        sb += __shfl_xor(sb, m);
    }
    if (lane == 0) {
        gw[h] = sg;
        c1[h] = sb + b1[h];
    }
}

// ---------------- kernel 1: fused score + online-softmax pooling ----------------
// One WG = 256 threads (4 waves) owns a contiguous slice of one segment.
// Per 32-row tile: stage bf16(f)+stats -> LDS; MFMA score GEMM (B streamed from
// L2 with 1-step prefetch); GELU/w2 epilogue -> s; online-softmax update; pool
// accumulate O += w*f from the LDS bf16 tile. Partials merged by combine_kernel.
__global__ __launch_bounds__(256, 4) void fused_kernel(
    const float* __restrict__ feats, const unsigned short* __restrict__ w1g,
    const float* __restrict__ gw, const float* __restrict__ c1,
    const float* __restrict__ w2, const float* __restrict__ b2,
    const int* __restrict__ offsets, float* __restrict__ partials, int N) {
    __shared__ unsigned short xs[ROWS][XSS];
    __shared__ float spart[4][ROWS];
    __shared__ float2 stats_s[ROWS];
    __shared__ float wbuf[ROWS];
    __shared__ float sMx, sDn, sAl;

    const int tid = threadIdx.x;
    const int wid = tid >> 6;      // 0..3
    const int lane = tid & 63;
    const int l31 = lane & 31;
    const int hi = lane >> 5;      // 0/1
    const int seg = blockIdx.x / PSEG;
    const int part = blockIdx.x % PSEG;
    const int st = offsets[seg];
    const int en = offsets[seg + 1];
    const int len = en - st;
    const int chunk = (len + PSEG - 1) / PSEG;
    const int rs = st + part * chunk;
    const int re = min(rs + chunk, en);
    const int nt = (re > rs) ? ((re - rs + ROWS - 1) / ROWS) : 0;

    // two 32-hid slices per wave
    const int hid0 = (wid * 2 + 0) * 32 + l31;
    const int hid1 = (wid * 2 + 1) * 32 + l31;
    const float gw0 = gw[hid0], gw1 = gw[hid1];
    const float c10 = c1[hid0], c11 = c1[hid1];
    const float w20 = w2[hid0], w21 = w2[hid1];
    const float b2v = b2[0];

    float O0 = 0.0f, O1 = 0.0f;
    if (tid == 0) { sMx = -3.0e38f; sDn = 0.0f; }

    const int srow4 = tid >> 4;   // 0..15
    const int schunk = tid & 15;  // 0..15

    for (int t = 0; t < nt; t++) {
        const int row0 = rs + t * ROWS;

        // ---- stage: 2 passes of 16 rows; fp32 load, stats, bf16 pack -> LDS --
#pragma unroll
        for (int p = 0; p < 2; p++) {
            const int r = p * 16 + srow4;
            size_t rg = (size_t)(row0 + r);
            if (rg >= (size_t)N) rg = (size_t)N - 1;
            const float* fp = feats + rg * IN_DIM + schunk * 4;
            float4 f[8];
#pragma unroll
            for (int j = 0; j < 8; j++) f[j] = *(const float4*)(fp + j * 64);
            float sf = 0.0f, qf = 0.0f;
#pragma unroll
            for (int j = 0; j < 8; j++) {
                sf += f[j].x + f[j].y + f[j].z + f[j].w;
                qf = fmaf(f[j].x, f[j].x, qf);
                qf = fmaf(f[j].y, f[j].y, qf);
                qf = fmaf(f[j].z, f[j].z, qf);
                qf = fmaf(f[j].w, f[j].w, qf);
            }
#pragma unroll
            for (int j = 0; j < 8; j++) {
                uint2 pk;
                pk.x = pack_bf2(f[j].x, f[j].y);
                pk.y = pack_bf2(f[j].z, f[j].w);
                *(uint2*)&xs[r][j * 64 + schunk * 4] = pk;
            }
#pragma unroll
            for (int m = 1; m < 16; m <<= 1) {
                sf += __shfl_xor(sf, m);
                qf += __shfl_xor(qf, m);
            }
            if (schunk == 0) {
                const float mu = sf * (1.0f / IN_DIM);
                const float var = fmaxf(qf * (1.0f / IN_DIM) - mu * mu, 0.0f);
                stats_s[r] = make_float2(mu, rsqrtf(var + 1e-5f));
            }
        }
        __syncthreads();  // B1: xs + stats ready

        // ---- GEMM: A from LDS, B streamed from L2 with 1-step prefetch ----
        floatx16 acc0 = (floatx16)(0.0f);
        floatx16 acc1 = (floatx16)(0.0f);
        {
            const unsigned short* bp0 = w1g + (size_t)hid0 * IN_DIM + hi * 8;
            const unsigned short* bp1 = w1g + (size_t)hid1 * IN_DIM + hi * 8;
            const unsigned short* ap = &xs[l31][hi * 8];
            bf16x8 b0 = __builtin_bit_cast(bf16x8, *(const ushort8*)bp0);
            bf16x8 b1 = __builtin_bit_cast(bf16x8, *(const ushort8*)bp1);
#pragma unroll 4
            for (int ki = 0; ki < 32; ki++) {
                const bf16x8 a = __builtin_bit_cast(bf16x8, *(const ushort8*)(ap + ki * 16));
                bf16x8 n0 = b0, n1 = b1;
                if (ki < 31) {
                    n0 = __builtin_bit_cast(bf16x8, *(const ushort8*)(bp0 + (ki + 1) * 16));
                    n1 = __builtin_bit_cast(bf16x8, *(const ushort8*)(bp1 + (ki + 1) * 16));
                }
                acc0 = __builtin_amdgcn_mfma_f32_32x32x16_bf16(a, b0, acc0, 0, 0, 0);
                acc1 = __builtin_amdgcn_mfma_f32_32x32x16_bf16(a, b1, acc1, 0, 0, 0);
                b0 = n0;
                b1 = n1;
            }
        }

        // ---- epilogue: LN affine + GELU + w2; butterfly over 32 hid lanes ----
        float tv[16];
#pragma unroll
        for (int r = 0; r < 16; r++) {
            const int row = (r & 3) + 8 * (r >> 2) + 4 * hi;
            const float2 stt = stats_s[row];
            const float h0 = stt.y * (acc0[r] - stt.x * gw0) + c10;
            const float h1 = stt.y * (acc1[r] - stt.x * gw1) + c11;
            tv[r] = gelu(h0) * w20 + gelu(h1) * w21;
        }
#pragma unroll
        for (int m = 1; m < 32; m <<= 1)
#pragma unroll
            for (int r = 0; r < 16; r++) tv[r] += __shfl_xor(tv[r], m);
        if (l31 == 0) {
#pragma unroll
            for (int r = 0; r < 16; r++)
                spart[wid][(r & 3) + 8 * (r >> 2) + 4 * hi] = tv[r];
        }
        __syncthreads();  // B2: spart ready

        // ---- online-softmax bookkeeping (wave 0, lanes 0..31) ----
        if (tid < 32) {
            float sv = spart[0][tid] + spart[1][tid] + spart[2][tid] + spart[3][tid] + b2v;
            if (row0 + tid >= re) sv = -3.0e38f;
            float mt = sv;
#pragma unroll
            for (int m = 1; m < 32; m <<= 1) mt = fmaxf(mt, __shfl_xor(mt, m));
            const float Mold = sMx;
            const float Mnew = fmaxf(Mold, mt);
            const float al = __expf(Mold - Mnew);
            const float w = __expf(sv - Mnew);
            wbuf[tid] = w;
            float wsum = w;
#pragma unroll
            for (int m = 1; m < 32; m <<= 1) wsum += __shfl_xor(wsum, m);
            if (tid == 0) {
                sDn = sDn * al + wsum;
                sMx = Mnew;
                sAl = al;
            }
        }
        __syncthreads();  // B3: wbuf, sAl ready

        // ---- pool accumulate: thread owns cols (2*tid, 2*tid+1) ----
        {
            const float al = sAl;
            O0 *= al;
            O1 *= al;
#pragma unroll 8
            for (int r = 0; r < ROWS; r++) {
                const unsigned int d = *(const unsigned int*)&xs[r][tid * 2];
                const float w = wbuf[r];
                O0 = fmaf(w, __uint_as_float(d << 16), O0);
                O1 = fmaf(w, __uint_as_float(d & 0xffff0000u), O1);
            }
        }
        __syncthreads();  // B4: xs free for next tile
    }

    float* pp = partials + (size_t)blockIdx.x * PSTRIDE;
    pp[2 * tid] = O0;
    pp[2 * tid + 1] = O1;
    if (tid == 0) {
        pp[512] = sMx;
        pp[513] = sDn;
    }
}

// ---------------- kernel 2: combine partials per segment ----------------
__global__ void combine_kernel(const float* __restrict__ partials, float* __restrict__ out) {
    const int seg = blockIdx.x;
    const int t = threadIdx.x;  // 256 threads, 2 cols each
    const float* base = partials + (size_t)seg * PSEG * PSTRIDE;
    float M = -3.0e38f;
#pragma unroll
    for (int p = 0; p < PSEG; p++) M = fmaxf(M, base[p * PSTRIDE + 512]);
    float D = 0.0f, a0 = 0.0f, a1 = 0.0f;
#pragma unroll
    for (int p = 0; p < PSEG; p++) {
        const float e = __expf(base[p * PSTRIDE + 512] - M);
        D += e * base[p * PSTRIDE + 513];
        a0 += e * base[p * PSTRIDE + 2 * t];
        a1 += e * base[p * PSTRIDE + 2 * t + 1];
    }
    out[(size_t)seg * IN_DIM + 2 * t] = a0 / D;
    out[(size_t)seg * IN_DIM + 2 * t + 1] = a1 / D;
}

extern "C" void kernel_launch(void* const* d_in, const int* in_sizes, int n_in,
                              void* d_out, int out_size, void* d_ws, size_t ws_size,
                              hipStream_t stream) {
    const float* feats = (const float*)d_in[0];
    const float* ln_g = (const float*)d_in[1];
    const float* ln_b = (const float*)d_in[2];
    const float* w1 = (const float*)d_in[3];
    const float* b1 = (const float*)d_in[4];
    const float* w2 = (const float*)d_in[5];
    const float* b2 = (const float*)d_in[6];
    const int* offsets = (const int*)d_in[7];
    const int N = in_sizes[0] / IN_DIM;
    const int nseg = in_sizes[7] - 1;
    float* out = (float*)d_out;

    // ws: [w1g bf16 256K][gw 1K][c1 1K][partials nseg*PSEG*PSTRIDE*4]
    char* ws = (char*)d_ws;
    unsigned short* w1g = (unsigned short*)ws;
    float* gw = (float*)(ws + (size_t)HID_DIM * IN_DIM * 2);
    float* c1 = gw + HID_DIM;
    float* partials = c1 + HID_DIM;

    prep_w1_kernel<<<HID_DIM / 4, 256, 0, stream>>>(w1, ln_g, ln_b, b1, w1g, gw, c1);
    fused_kernel<<<nseg * PSEG, 256, 0, stream>>>(feats, w1g, gw, c1, w2, b2, offsets,
                                                  partials, N);
    combine_kernel<<<nseg, 256, 0, stream>>>(partials, out);
}